// Round 7
// baseline (350.542 us; speedup 1.0000x reference)
//
#include <hip/hip_runtime.h>

#define N_RET  200000
#define N_ORIG 100000
#define N_EDGE 800000
#define NB_RET  ((N_RET  + 511) >> 9)   // 391 buckets of 512 nodes
#define NB_ORIG ((N_ORIG + 511) >> 9)   // 196
#define NBIN    ((N_EDGE + 8191) / 8192) // 98 edge-chunk blocks

typedef __attribute__((ext_vector_type(8))) short bf16x8;   // 8 bf16 (4 VGPRs)
typedef __attribute__((ext_vector_type(4))) float f32x4;    // MFMA C/D

__device__ __forceinline__ ushort f2bf(float f) {
    union { float f; unsigned u; } v; v.f = f;
    unsigned r = v.u + 0x7FFFu + ((v.u >> 16) & 1u);   // RNE
    return (ushort)(r >> 16);
}
__device__ __forceinline__ float bf2f(ushort u) {
    union { unsigned u; float f; } v; v.u = ((unsigned)u) << 16;
    return v.f;
}
__device__ __forceinline__ int swz(int byteoff) {   // XOR swizzle for LDS A-tiles
    return byteoff ^ ((byteoff >> 4) & 0x70);
}

// ---------------- prep: all 4 weight transposes (bf16) + zero bucket counters ----------------
__global__ void prep_kernel(const float* __restrict__ Wl1, const float* __restrict__ Wr1,
                            const float* __restrict__ Wg2, const float* __restrict__ Wout,
                            ushort* __restrict__ wtl1, ushort* __restrict__ wtr1,
                            ushort* __restrict__ wtg2, ushort* __restrict__ wto,
                            int* __restrict__ bcnt) {
    const int b = blockIdx.x, t = threadIdx.x;
    if (b == 224) {
        for (int i = t; i < 1024; i += 256) bcnt[i] = 0;
        return;
    }
    const float* W; ushort* WT; int base, nshift;
    if (b < 64)       { W = Wl1;  WT = wtl1; base = b;       nshift = 7; }
    else if (b < 128) { W = Wr1;  WT = wtr1; base = b - 64;  nshift = 7; }
    else if (b < 192) { W = Wg2;  WT = wtg2; base = b - 128; nshift = 7; }
    else              { W = Wout; WT = wto;  base = b - 192; nshift = 6; }
    int i = base * 256 + t;
    int k = i >> nshift, n = i & ((1 << nshift) - 1);
    WT[n * 128 + k] = f2bf(W[i]);   // K = 128 for all
}

// ---------------- bucket-level histogram (both directions in one pass) ----------------
__global__ __launch_bounds__(256) void bucket_count(const int* __restrict__ ridx,
                                                    const int* __restrict__ cidx,
                                                    int* __restrict__ bcnt1,
                                                    int* __restrict__ bcnt2) {
    __shared__ int h1[512], h2[512];
    const int t = threadIdx.x;
    const int c0 = blockIdx.x * 8192;
    for (int i = t; i < 512; i += 256) { h1[i] = 0; h2[i] = 0; }
    __syncthreads();
    for (int i = t; i < 8192; i += 256) {
        int e = c0 + i;
        if (e < N_EDGE) {
            atomicAdd(&h1[ridx[e] >> 9], 1);
            atomicAdd(&h2[cidx[e] >> 9], 1);
        }
    }
    __syncthreads();
    for (int b = t; b < NB_RET; b += 256)
        if (h1[b]) atomicAdd(&bcnt1[b], h1[b]);
    for (int b = t; b < NB_ORIG; b += 256)
        if (h2[b]) atomicAdd(&bcnt2[b], h2[b]);
}

// ---------------- single-block scan of bucket counts -> bucket offsets + cursors ----------------
__global__ __launch_bounds__(256) void scan_buckets(const int* __restrict__ bcnt1,
                                                    int* __restrict__ boff1, int* __restrict__ bcur1,
                                                    const int* __restrict__ bcnt2,
                                                    int* __restrict__ boff2, int* __restrict__ bcur2,
                                                    int* __restrict__ off_ret,
                                                    int* __restrict__ off_orig) {
    __shared__ int sm[256];
    const int t = threadIdx.x;
    {
        int a0 = (2 * t     < NB_RET) ? bcnt1[2 * t]     : 0;
        int a1 = (2 * t + 1 < NB_RET) ? bcnt1[2 * t + 1] : 0;
        sm[t] = a0 + a1;
        __syncthreads();
        for (int d = 1; d < 256; d <<= 1) {
            int v = (t >= d) ? sm[t - d] : 0;
            __syncthreads(); sm[t] += v; __syncthreads();
        }
        int tb = t ? sm[t - 1] : 0;
        if (2 * t < NB_RET)     { boff1[2 * t]     = tb;      bcur1[2 * t]     = tb; }
        if (2 * t + 1 < NB_RET) { boff1[2 * t + 1] = tb + a0; bcur1[2 * t + 1] = tb + a0; }
        if (t == 0) { boff1[NB_RET] = N_EDGE; off_ret[N_RET] = N_EDGE; }
        __syncthreads();
    }
    {
        int a0 = (2 * t     < NB_ORIG) ? bcnt2[2 * t]     : 0;
        int a1 = (2 * t + 1 < NB_ORIG) ? bcnt2[2 * t + 1] : 0;
        sm[t] = a0 + a1;
        __syncthreads();
        for (int d = 1; d < 256; d <<= 1) {
            int v = (t >= d) ? sm[t - d] : 0;
            __syncthreads(); sm[t] += v; __syncthreads();
        }
        int tb = t ? sm[t - 1] : 0;
        if (2 * t < NB_ORIG)     { boff2[2 * t]     = tb;      bcur2[2 * t]     = tb; }
        if (2 * t + 1 < NB_ORIG) { boff2[2 * t + 1] = tb + a0; bcur2[2 * t + 1] = tb + a0; }
        if (t == 0) { boff2[NB_ORIG] = N_EDGE; off_orig[N_ORIG] = N_EDGE; }
    }
}

// ---------------- pass A (both dirs): bin edges by dst bucket; record (local_dst<<18)|src ----------------
__global__ __launch_bounds__(256) void bin_both(const int* __restrict__ ridx,
                                                const int* __restrict__ cidx,
                                                int* __restrict__ bcur1, int* __restrict__ bcur2,
                                                int* __restrict__ binned1, int* __restrict__ binned2) {
    __shared__ int hist[512], base[512], lcur[512];
    const int t = threadIdx.x;
    const bool second = blockIdx.x >= NBIN;
    const int* dst = second ? cidx : ridx;
    const int* src = second ? ridx : cidx;
    int* bcur = second ? bcur2 : bcur1;
    int* binned = second ? binned2 : binned1;
    const int nbuckets = second ? NB_ORIG : NB_RET;
    const int c0 = (second ? blockIdx.x - NBIN : blockIdx.x) * 8192;
    for (int i = t; i < 512; i += 256) { hist[i] = 0; lcur[i] = 0; }
    __syncthreads();
    for (int i = t; i < 8192; i += 256) {
        int e = c0 + i;
        if (e < N_EDGE) atomicAdd(&hist[dst[e] >> 9], 1);
    }
    __syncthreads();
    for (int b = t; b < nbuckets; b += 256)
        base[b] = hist[b] > 0 ? atomicAdd(&bcur[b], hist[b]) : 0;
    __syncthreads();
    for (int i = t; i < 8192; i += 256) {
        int e = c0 + i;
        if (e < N_EDGE) {
            int d = dst[e];
            int b = d >> 9;
            int r = atomicAdd(&lcur[b], 1);
            binned[base[b] + r] = ((d & 511) << 18) | src[e];
        }
    }
}

// ---------------- pass B (both dirs): per-bucket node-offset build + CSR fill ----------------
__global__ __launch_bounds__(256) void fill_both(const int* __restrict__ binned1,
                                                 const int* __restrict__ boff1,
                                                 int* __restrict__ off_ret, int* __restrict__ el1,
                                                 const int* __restrict__ binned2,
                                                 const int* __restrict__ boff2,
                                                 int* __restrict__ off_orig, int* __restrict__ el2) {
    __shared__ int hist[512];
    __shared__ int sm[256];
    const int t = threadIdx.x;
    const bool second = blockIdx.x >= NB_RET;
    const int bkt = second ? blockIdx.x - NB_RET : blockIdx.x;
    const int* binned = second ? binned2 : binned1;
    const int* boff = second ? boff2 : boff1;
    int* off = second ? off_orig : off_ret;
    int* el  = second ? el2 : el1;
    const int nnodes = second ? N_ORIG : N_RET;
    const int base = bkt << 9;
    const int nvalid = min(512, nnodes - base);
    const int s0 = boff[bkt], s1 = boff[bkt + 1];
    for (int i = t; i < 512; i += 256) hist[i] = 0;
    __syncthreads();
    for (int i = s0 + t; i < s1; i += 256)
        atomicAdd(&hist[binned[i] >> 18], 1);
    __syncthreads();
    int a0 = hist[2 * t], a1 = hist[2 * t + 1];
    sm[t] = a0 + a1;
    __syncthreads();
    for (int d = 1; d < 256; d <<= 1) {
        int v = (t >= d) ? sm[t - d] : 0;
        __syncthreads(); sm[t] += v; __syncthreads();
    }
    int tb = (t ? sm[t - 1] : 0) + s0;
    if (2 * t < nvalid)     off[base + 2 * t]     = tb;
    if (2 * t + 1 < nvalid) off[base + 2 * t + 1] = tb + a0;
    hist[2 * t] = tb;
    hist[2 * t + 1] = tb + a0;
    __syncthreads();
    for (int i = s0 + t; i < s1; i += 256) {
        int v = binned[i];
        int p = atomicAdd(&hist[v >> 18], 1);
        el[p] = v & 0x3FFFF;
    }
}

// ---------------- GEMM (f32 A, global-resident W^T, bf16 out): out = bf16(A @ W) ----------------
// B-fragments read straight from global WT (32 KB, L1-resident) — no W LDS tile.
__global__ __launch_bounds__(256) void gemm_f32a(const float4* __restrict__ A,
                                                 const ushort* __restrict__ WT,
                                                 ushort* __restrict__ outp, int M) {
    __shared__ ushort Alds[64 * 128];    // 16 KB
    const int t = threadIdx.x;
    const int i0 = blockIdx.x * 64;

    #pragma unroll
    for (int it = 0; it < 8; ++it) {
        int row = (t >> 5) + 8 * it;
        int q = t & 31;
        int gr = min(i0 + row, M - 1);
        float4 v = A[(size_t)gr * 32 + q];
        ushort4 b; b.x = f2bf(v.x); b.y = f2bf(v.y); b.z = f2bf(v.z); b.w = f2bf(v.w);
        *(ushort4*)&Alds[swz(row * 256 + q * 8) >> 1] = b;
    }
    __syncthreads();

    const int w = t >> 6, l = t & 63;
    const int r16 = l & 15, kg = l >> 4;
    const int arow = 16 * w + r16;

    bf16x8 a[4];
    #pragma unroll
    for (int ks = 0; ks < 4; ++ks)
        a[ks] = *(const bf16x8*)&Alds[swz(arow * 256 + kg * 16 + ks * 64) >> 1];
    f32x4 acc[8];
    #pragma unroll
    for (int cf = 0; cf < 8; ++cf) acc[cf] = (f32x4){0.f, 0.f, 0.f, 0.f};
    #pragma unroll
    for (int cf = 0; cf < 8; ++cf) {
        int n = cf * 16 + r16;
        #pragma unroll
        for (int ks = 0; ks < 4; ++ks) {
            bf16x8 b = *(const bf16x8*)&WT[n * 128 + kg * 8 + ks * 32];
            acc[cf] = __builtin_amdgcn_mfma_f32_16x16x32_bf16(a[ks], b, acc[cf], 0, 0, 0);
        }
    }
    #pragma unroll
    for (int r = 0; r < 4; ++r) {
        int gr = i0 + 16 * w + 4 * kg + r;
        if (gr >= M) continue;
        #pragma unroll
        for (int cf = 0; cf < 8; ++cf)
            outp[(size_t)gr * 128 + cf * 16 + r16] = f2bf(acc[cf][r]);
    }
}

// ---------------- gather + SAGE epilogue: r1s = bf16(relu(mean_agg(ho) + xr + bl) * inv_s) ----------------
__global__ void gather_sage(const ushort* __restrict__ ho, const ushort* __restrict__ xr,
                            const int* __restrict__ off, const int* __restrict__ slist,
                            const float* __restrict__ bl, ushort* __restrict__ r1s) {
    int gt = blockIdx.x * 256 + threadIdx.x;
    int node = gt >> 4;
    if (node >= N_RET) return;
    int o8 = gt & 15;
    int s = off[node], e = off[node + 1];
    float acc[8] = {0.f, 0.f, 0.f, 0.f, 0.f, 0.f, 0.f, 0.f};
    for (int i = s; i < e; ++i) {
        int sn = slist[i];
        bf16x8 v = *(const bf16x8*)&ho[(size_t)sn * 128 + o8 * 8];
        #pragma unroll
        for (int j = 0; j < 8; ++j) acc[j] += bf2f((ushort)v[j]);
    }
    int deg = e - s;
    float rinv = 1.0f / fmaxf((float)deg, 1.0f);
    float sinv = deg > 0 ? rsqrtf((float)deg) : 0.f;
    bf16x8 xv = *(const bf16x8*)&xr[(size_t)node * 128 + o8 * 8];
    bf16x8 ov;
    #pragma unroll
    for (int j = 0; j < 8; ++j) {
        float v = fmaxf(acc[j] * rinv + bf2f((ushort)xv[j]) + bl[o8 * 8 + j], 0.f) * sinv;
        ov[j] = (short)f2bf(v);
    }
    *(bf16x8*)&r1s[(size_t)node * 128 + o8 * 8] = ov;
}

// ---- fused: g=sum(r1s); t=relu(g@Wg2*inv_d+bg2); out=t@Wout+bout   [100k rows] ----
// Only a 16 KB A-tile in LDS; both weight matrices read from global (L1-resident).
__global__ __launch_bounds__(256) void gemm_t_out(
    const ushort* __restrict__ r1s, const ushort* __restrict__ WTg,
    const ushort* __restrict__ WTo, const int* __restrict__ off,
    const int* __restrict__ el, const float* __restrict__ bg,
    const float* __restrict__ bo, float* __restrict__ out, int M) {
    __shared__ ushort Alds[64 * 128];    // 16 KB
    const int t = threadIdx.x;
    const int i0 = blockIdx.x * 64;

    // gather-sum r1s rows -> Alds (bf16, swizzled)
    const int o8 = t & 15;
    #pragma unroll
    for (int pass = 0; pass < 4; ++pass) {
        int row = pass * 16 + (t >> 4);
        int gr = min(i0 + row, M - 1);
        int s = off[gr], e = off[gr + 1];
        float a8[8] = {0.f, 0.f, 0.f, 0.f, 0.f, 0.f, 0.f, 0.f};
        for (int i = s; i < e; ++i) {
            int sn = el[i];
            bf16x8 v = *(const bf16x8*)&r1s[(size_t)sn * 128 + o8 * 8];
            #pragma unroll
            for (int j = 0; j < 8; ++j) a8[j] += bf2f((ushort)v[j]);
        }
        bf16x8 ov;
        #pragma unroll
        for (int j = 0; j < 8; ++j) ov[j] = (short)f2bf(a8[j]);
        *(bf16x8*)&Alds[swz(row * 256 + o8 * 16) >> 1] = ov;
    }
    __syncthreads();

    const int w = t >> 6, l = t & 63;
    const int r16 = l & 15, kg = l >> 4;
    const int arow = 16 * w + r16;

    bf16x8 a[4];
    #pragma unroll
    for (int ks = 0; ks < 4; ++ks)
        a[ks] = *(const bf16x8*)&Alds[swz(arow * 256 + kg * 16 + ks * 64) >> 1];
    f32x4 acc[8];
    #pragma unroll
    for (int cf = 0; cf < 8; ++cf) acc[cf] = (f32x4){0.f, 0.f, 0.f, 0.f};
    #pragma unroll
    for (int cf = 0; cf < 8; ++cf) {
        int n = cf * 16 + r16;
        #pragma unroll
        for (int ks = 0; ks < 4; ++ks) {
            bf16x8 b = *(const bf16x8*)&WTg[n * 128 + kg * 8 + ks * 32];
            acc[cf] = __builtin_amdgcn_mfma_f32_16x16x32_bf16(a[ks], b, acc[cf], 0, 0, 0);
        }
    }
    __syncthreads();   // all a-frags consumed; Alds free for the t-tile

    // epilogue1: t-tile = relu(acc*inv_d + bg) -> back into Alds (bf16, swizzled)
    #pragma unroll
    for (int r = 0; r < 4; ++r) {
        int row = 16 * w + 4 * kg + r;
        int grc = min(i0 + row, M - 1);
        int dg = off[grc + 1] - off[grc];
        float di = dg > 0 ? rsqrtf((float)dg) : 0.f;
        #pragma unroll
        for (int cf = 0; cf < 8; ++cf) {
            int col = cf * 16 + r16;
            float v = fmaxf(acc[cf][r] * di + bg[col], 0.f);
            Alds[swz(row * 256 + col * 2) >> 1] = f2bf(v);
        }
    }
    __syncthreads();

    bf16x8 a2[4];
    #pragma unroll
    for (int ks = 0; ks < 4; ++ks)
        a2[ks] = *(const bf16x8*)&Alds[swz(arow * 256 + kg * 16 + ks * 64) >> 1];
    f32x4 acc2[4];
    #pragma unroll
    for (int cf = 0; cf < 4; ++cf) acc2[cf] = (f32x4){0.f, 0.f, 0.f, 0.f};
    #pragma unroll
    for (int cf = 0; cf < 4; ++cf) {
        int n = cf * 16 + r16;
        #pragma unroll
        for (int ks = 0; ks < 4; ++ks) {
            bf16x8 b = *(const bf16x8*)&WTo[n * 128 + kg * 8 + ks * 32];
            acc2[cf] = __builtin_amdgcn_mfma_f32_16x16x32_bf16(a2[ks], b, acc2[cf], 0, 0, 0);
        }
    }
    #pragma unroll
    for (int r = 0; r < 4; ++r) {
        int gr = i0 + 16 * w + 4 * kg + r;
        if (gr >= M) continue;
        #pragma unroll
        for (int cf = 0; cf < 4; ++cf) {
            int col = cf * 16 + r16;
            out[(size_t)gr * 64 + col] = acc2[cf][r] + bo[col];
        }
    }
}

extern "C" void kernel_launch(void* const* d_in, const int* in_sizes, int n_in,
                              void* d_out, int out_size, void* d_ws, size_t ws_size,
                              hipStream_t stream) {
    const float* x_ret    = (const float*)d_in[0];
    const float* x_orig   = (const float*)d_in[1];
    const int*   ret_idx  = (const int*)d_in[2];
    const int*   orig_idx = (const int*)d_in[3];
    const float* Wl1  = (const float*)d_in[6];
    const float* bl1  = (const float*)d_in[7];
    const float* Wr1  = (const float*)d_in[8];
    const float* Wg2  = (const float*)d_in[9];
    const float* bg2  = (const float*)d_in[10];
    const float* Wout = (const float*)d_in[14];
    const float* bout = (const float*)d_in[15];
    float* out = (float*)d_out;

    // workspace layout
    ushort* hoB  = (ushort*)d_ws;                       // 100k*128 bf16
    ushort* xrB  = hoB + (size_t)N_ORIG * 128;          // 200k*128 bf16
    ushort* r1sB = xrB + (size_t)N_RET * 128;           // 200k*128 bf16
    ushort* wtl1 = r1sB + (size_t)N_RET * 128;          // 16384
    ushort* wtr1 = wtl1 + 16384;                        // 16384
    ushort* wtg2 = wtr1 + 16384;                        // 16384
    ushort* wto  = wtg2 + 16384;                        // 8192
    int* off_ret  = (int*)(wto + 8192);                 // N_RET+1
    int* off_orig = off_ret + N_RET + 1;                // N_ORIG+1
    int* bcnt1    = off_orig + N_ORIG + 1;              // 512
    int* bcnt2    = bcnt1 + 512;                        // 512 (adjacent for one-pass zero)
    int* boff1    = bcnt2 + 512;                        // 512
    int* boff2    = boff1 + 512;                        // 512
    int* bcur1    = boff2 + 512;                        // 512
    int* bcur2    = bcur1 + 512;                        // 512
    int* el1      = bcur2 + 512;                        // N_EDGE (src=orig, grouped by ret)
    int* el2      = el1 + N_EDGE;                       // N_EDGE (src=ret, grouped by orig)
    int* binned1  = el2 + N_EDGE;                       // N_EDGE packed
    int* binned2  = binned1 + N_EDGE;                   // N_EDGE packed

    prep_kernel<<<225, 256, 0, stream>>>(Wl1, Wr1, Wg2, Wout, wtl1, wtr1, wtg2, wto, bcnt1);

    bucket_count<<<NBIN, 256, 0, stream>>>(ret_idx, orig_idx, bcnt1, bcnt2);
    scan_buckets<<<1, 256, 0, stream>>>(bcnt1, boff1, bcur1, bcnt2, boff2, bcur2,
                                        off_ret, off_orig);
    bin_both<<<2 * NBIN, 256, 0, stream>>>(ret_idx, orig_idx, bcur1, bcur2, binned1, binned2);
    fill_both<<<NB_RET + NB_ORIG, 256, 0, stream>>>(binned1, boff1, off_ret, el1,
                                                    binned2, boff2, off_orig, el2);

    // ho = bf16(x_orig @ Wl1)    [100k x 128]
    gemm_f32a<<<(N_ORIG + 63) / 64, 256, 0, stream>>>((const float4*)x_orig, wtl1, hoB, N_ORIG);
    // xr = bf16(x_ret @ Wr1)     [200k x 128]
    gemm_f32a<<<(N_RET + 63) / 64, 256, 0, stream>>>((const float4*)x_ret, wtr1, xrB, N_RET);

    // r1s = bf16(relu(mean_agg(ho) + xr + bl1) * inv_s)   [200k x 128]
    gather_sage<<<(N_RET * 16) / 256, 256, 0, stream>>>(hoB, xrB, off_ret, el1, bl1, r1sB);

    // out = (relu(sum_agg(r1s)@Wg2*inv_d + bg2)) @ Wout + bout   [100k x 64]
    gemm_t_out<<<(N_ORIG + 63) / 64, 256, 0, stream>>>(r1sB, wtg2, wto, off_orig, el2,
                                                       bg2, bout, out, N_ORIG);
}

// Round 8
// 241.141 us; speedup vs baseline: 1.4537x; 1.4537x over previous
//
#include <hip/hip_runtime.h>

#define N_RET  200000
#define N_ORIG 100000
#define N_EDGE 800000
#define NB_RET  ((N_RET  + 511) >> 9)   // 391 buckets of 512 nodes
#define NB_ORIG ((N_ORIG + 511) >> 9)   // 196
#define NBIN    ((N_EDGE + 8191) / 8192) // 98 edge-chunk blocks
#define NBLK_HO ((N_ORIG + 63) / 64)    // 1563
#define NBLK_XR ((N_RET + 63) / 64)     // 3125

typedef __attribute__((ext_vector_type(8))) short bf16x8;   // 8 bf16 (4 VGPRs)
typedef __attribute__((ext_vector_type(4))) float f32x4;    // MFMA C/D

__device__ __forceinline__ ushort f2bf(float f) {
    union { float f; unsigned u; } v; v.f = f;
    unsigned r = v.u + 0x7FFFu + ((v.u >> 16) & 1u);   // RNE
    return (ushort)(r >> 16);
}
__device__ __forceinline__ float bf2f(ushort u) {
    union { unsigned u; float f; } v; v.u = ((unsigned)u) << 16;
    return v.f;
}
__device__ __forceinline__ int swz(int byteoff) {   // XOR swizzle for LDS tiles
    return byteoff ^ ((byteoff >> 4) & 0x70);
}

// ---------------- prep: all 4 weight transposes (bf16) + zero bucket counters ----------------
__global__ void prep_kernel(const float* __restrict__ Wl1, const float* __restrict__ Wr1,
                            const float* __restrict__ Wg2, const float* __restrict__ Wout,
                            ushort* __restrict__ wtl1, ushort* __restrict__ wtr1,
                            ushort* __restrict__ wtg2, ushort* __restrict__ wto,
                            int* __restrict__ bcnt) {
    const int b = blockIdx.x, t = threadIdx.x;
    if (b == 224) {
        for (int i = t; i < 1024; i += 256) bcnt[i] = 0;
        return;
    }
    const float* W; ushort* WT; int base, nshift;
    if (b < 64)       { W = Wl1;  WT = wtl1; base = b;       nshift = 7; }
    else if (b < 128) { W = Wr1;  WT = wtr1; base = b - 64;  nshift = 7; }
    else if (b < 192) { W = Wg2;  WT = wtg2; base = b - 128; nshift = 7; }
    else              { W = Wout; WT = wto;  base = b - 192; nshift = 6; }
    int i = base * 256 + t;
    int k = i >> nshift, n = i & ((1 << nshift) - 1);
    WT[n * 128 + k] = f2bf(W[i]);   // K = 128 for all
}

// ---------------- bucket-level histogram (both directions in one pass) ----------------
__global__ __launch_bounds__(256) void bucket_count(const int* __restrict__ ridx,
                                                    const int* __restrict__ cidx,
                                                    int* __restrict__ bcnt1,
                                                    int* __restrict__ bcnt2) {
    __shared__ int h1[512], h2[512];
    const int t = threadIdx.x;
    const int c0 = blockIdx.x * 8192;
    for (int i = t; i < 512; i += 256) { h1[i] = 0; h2[i] = 0; }
    __syncthreads();
    for (int i = t; i < 8192; i += 256) {
        int e = c0 + i;
        if (e < N_EDGE) {
            atomicAdd(&h1[ridx[e] >> 9], 1);
            atomicAdd(&h2[cidx[e] >> 9], 1);
        }
    }
    __syncthreads();
    for (int b = t; b < NB_RET; b += 256)
        if (h1[b]) atomicAdd(&bcnt1[b], h1[b]);
    for (int b = t; b < NB_ORIG; b += 256)
        if (h2[b]) atomicAdd(&bcnt2[b], h2[b]);
}

// ---------------- single-block scan of bucket counts -> bucket offsets + cursors ----------------
__global__ __launch_bounds__(256) void scan_buckets(const int* __restrict__ bcnt1,
                                                    int* __restrict__ boff1, int* __restrict__ bcur1,
                                                    const int* __restrict__ bcnt2,
                                                    int* __restrict__ boff2, int* __restrict__ bcur2,
                                                    int* __restrict__ off_ret,
                                                    int* __restrict__ off_orig) {
    __shared__ int sm[256];
    const int t = threadIdx.x;
    {
        int a0 = (2 * t     < NB_RET) ? bcnt1[2 * t]     : 0;
        int a1 = (2 * t + 1 < NB_RET) ? bcnt1[2 * t + 1] : 0;
        sm[t] = a0 + a1;
        __syncthreads();
        for (int d = 1; d < 256; d <<= 1) {
            int v = (t >= d) ? sm[t - d] : 0;
            __syncthreads(); sm[t] += v; __syncthreads();
        }
        int tb = t ? sm[t - 1] : 0;
        if (2 * t < NB_RET)     { boff1[2 * t]     = tb;      bcur1[2 * t]     = tb; }
        if (2 * t + 1 < NB_RET) { boff1[2 * t + 1] = tb + a0; bcur1[2 * t + 1] = tb + a0; }
        if (t == 0) { boff1[NB_RET] = N_EDGE; off_ret[N_RET] = N_EDGE; }
        __syncthreads();
    }
    {
        int a0 = (2 * t     < NB_ORIG) ? bcnt2[2 * t]     : 0;
        int a1 = (2 * t + 1 < NB_ORIG) ? bcnt2[2 * t + 1] : 0;
        sm[t] = a0 + a1;
        __syncthreads();
        for (int d = 1; d < 256; d <<= 1) {
            int v = (t >= d) ? sm[t - d] : 0;
            __syncthreads(); sm[t] += v; __syncthreads();
        }
        int tb = t ? sm[t - 1] : 0;
        if (2 * t < NB_ORIG)     { boff2[2 * t]     = tb;      bcur2[2 * t]     = tb; }
        if (2 * t + 1 < NB_ORIG) { boff2[2 * t + 1] = tb + a0; bcur2[2 * t + 1] = tb + a0; }
        if (t == 0) { boff2[NB_ORIG] = N_EDGE; off_orig[N_ORIG] = N_EDGE; }
    }
}

// ---------------- pass A (both dirs): bin edges by dst bucket; record (local_dst<<18)|src ----------------
__global__ __launch_bounds__(256) void bin_both(const int* __restrict__ ridx,
                                                const int* __restrict__ cidx,
                                                int* __restrict__ bcur1, int* __restrict__ bcur2,
                                                int* __restrict__ binned1, int* __restrict__ binned2) {
    __shared__ int hist[512], base[512], lcur[512];
    const int t = threadIdx.x;
    const bool second = blockIdx.x >= NBIN;
    const int* dst = second ? cidx : ridx;
    const int* src = second ? ridx : cidx;
    int* bcur = second ? bcur2 : bcur1;
    int* binned = second ? binned2 : binned1;
    const int nbuckets = second ? NB_ORIG : NB_RET;
    const int c0 = (second ? blockIdx.x - NBIN : blockIdx.x) * 8192;
    for (int i = t; i < 512; i += 256) { hist[i] = 0; lcur[i] = 0; }
    __syncthreads();
    for (int i = t; i < 8192; i += 256) {
        int e = c0 + i;
        if (e < N_EDGE) atomicAdd(&hist[dst[e] >> 9], 1);
    }
    __syncthreads();
    for (int b = t; b < nbuckets; b += 256)
        base[b] = hist[b] > 0 ? atomicAdd(&bcur[b], hist[b]) : 0;
    __syncthreads();
    for (int i = t; i < 8192; i += 256) {
        int e = c0 + i;
        if (e < N_EDGE) {
            int d = dst[e];
            int b = d >> 9;
            int r = atomicAdd(&lcur[b], 1);
            binned[base[b] + r] = ((d & 511) << 18) | src[e];
        }
    }
}

// ---------------- pass B (both dirs): per-bucket node-offset build + CSR fill ----------------
__global__ __launch_bounds__(256) void fill_both(const int* __restrict__ binned1,
                                                 const int* __restrict__ boff1,
                                                 int* __restrict__ off_ret, int* __restrict__ el1,
                                                 const int* __restrict__ binned2,
                                                 const int* __restrict__ boff2,
                                                 int* __restrict__ off_orig, int* __restrict__ el2) {
    __shared__ int hist[512];
    __shared__ int sm[256];
    const int t = threadIdx.x;
    const bool second = blockIdx.x >= NB_RET;
    const int bkt = second ? blockIdx.x - NB_RET : blockIdx.x;
    const int* binned = second ? binned2 : binned1;
    const int* boff = second ? boff2 : boff1;
    int* off = second ? off_orig : off_ret;
    int* el  = second ? el2 : el1;
    const int nnodes = second ? N_ORIG : N_RET;
    const int base = bkt << 9;
    const int nvalid = min(512, nnodes - base);
    const int s0 = boff[bkt], s1 = boff[bkt + 1];
    for (int i = t; i < 512; i += 256) hist[i] = 0;
    __syncthreads();
    for (int i = s0 + t; i < s1; i += 256)
        atomicAdd(&hist[binned[i] >> 18], 1);
    __syncthreads();
    int a0 = hist[2 * t], a1 = hist[2 * t + 1];
    sm[t] = a0 + a1;
    __syncthreads();
    for (int d = 1; d < 256; d <<= 1) {
        int v = (t >= d) ? sm[t - d] : 0;
        __syncthreads(); sm[t] += v; __syncthreads();
    }
    int tb = (t ? sm[t - 1] : 0) + s0;
    if (2 * t < nvalid)     off[base + 2 * t]     = tb;
    if (2 * t + 1 < nvalid) off[base + 2 * t + 1] = tb + a0;
    hist[2 * t] = tb;
    hist[2 * t + 1] = tb + a0;
    __syncthreads();
    for (int i = s0 + t; i < s1; i += 256) {
        int v = binned[i];
        int p = atomicAdd(&hist[v >> 18], 1);
        el[p] = v & 0x3FFFF;
    }
}

// ---------------- merged linear GEMMs: ho = bf16(x_orig@Wl1), xr = bf16(x_ret@Wr1) ----------------
// One dispatch; block range selects the problem. W^T staged in LDS (R5-proven layout).
__global__ __launch_bounds__(256) void gemm_lin(const float4* __restrict__ Ao,
                                                const float4* __restrict__ Ar,
                                                const ushort* __restrict__ WTl,
                                                const ushort* __restrict__ WTr,
                                                ushort* __restrict__ hoB,
                                                ushort* __restrict__ xrB) {
    __shared__ ushort Alds[64 * 128];    // 16 KB
    __shared__ ushort Wlds[128 * 128];   // 32 KB
    const int t = threadIdx.x;
    const bool second = blockIdx.x >= NBLK_HO;
    const float4* A = second ? Ar : Ao;
    const ushort* WT = second ? WTr : WTl;
    ushort* outp = second ? xrB : hoB;
    const int M = second ? N_RET : N_ORIG;
    const int i0 = (second ? blockIdx.x - NBLK_HO : blockIdx.x) * 64;

    #pragma unroll
    for (int it = 0; it < 8; ++it) {
        int idx = t + 256 * it;
        int n = idx >> 4, u = idx & 15;
        *(bf16x8*)&Wlds[swz(n * 256 + u * 16) >> 1] = *(const bf16x8*)&WT[idx * 8];
    }
    #pragma unroll
    for (int it = 0; it < 8; ++it) {
        int row = (t >> 5) + 8 * it;
        int q = t & 31;
        int gr = min(i0 + row, M - 1);
        float4 v = A[(size_t)gr * 32 + q];
        ushort4 b; b.x = f2bf(v.x); b.y = f2bf(v.y); b.z = f2bf(v.z); b.w = f2bf(v.w);
        *(ushort4*)&Alds[swz(row * 256 + q * 8) >> 1] = b;
    }
    __syncthreads();

    const int w = t >> 6, l = t & 63;
    const int r16 = l & 15, kg = l >> 4;
    const int arow = 16 * w + r16;

    bf16x8 a[4];
    #pragma unroll
    for (int ks = 0; ks < 4; ++ks)
        a[ks] = *(const bf16x8*)&Alds[swz(arow * 256 + kg * 16 + ks * 64) >> 1];
    f32x4 acc[8];
    #pragma unroll
    for (int cf = 0; cf < 8; ++cf) acc[cf] = (f32x4){0.f, 0.f, 0.f, 0.f};
    #pragma unroll
    for (int cf = 0; cf < 8; ++cf) {
        int n = cf * 16 + r16;
        #pragma unroll
        for (int ks = 0; ks < 4; ++ks) {
            bf16x8 b = *(const bf16x8*)&Wlds[swz(n * 256 + kg * 16 + ks * 64) >> 1];
            acc[cf] = __builtin_amdgcn_mfma_f32_16x16x32_bf16(a[ks], b, acc[cf], 0, 0, 0);
        }
    }
    #pragma unroll
    for (int r = 0; r < 4; ++r) {
        int gr = i0 + 16 * w + 4 * kg + r;
        if (gr >= M) continue;
        #pragma unroll
        for (int cf = 0; cf < 8; ++cf)
            outp[(size_t)gr * 128 + cf * 16 + r16] = f2bf(acc[cf][r]);
    }
}

// ---------------- gather + SAGE epilogue: r1s = bf16(relu(mean_agg(ho) + xr + bl) * inv_s) ----------------
__global__ void gather_sage(const ushort* __restrict__ ho, const ushort* __restrict__ xr,
                            const int* __restrict__ off, const int* __restrict__ slist,
                            const float* __restrict__ bl, ushort* __restrict__ r1s) {
    int gt = blockIdx.x * 256 + threadIdx.x;
    int node = gt >> 4;
    if (node >= N_RET) return;
    int o8 = gt & 15;
    int s = off[node], e = off[node + 1];
    float acc[8] = {0.f, 0.f, 0.f, 0.f, 0.f, 0.f, 0.f, 0.f};
    for (int i = s; i < e; ++i) {
        int sn = slist[i];
        bf16x8 v = *(const bf16x8*)&ho[(size_t)sn * 128 + o8 * 8];
        #pragma unroll
        for (int j = 0; j < 8; ++j) acc[j] += bf2f((ushort)v[j]);
    }
    int deg = e - s;
    float rinv = 1.0f / fmaxf((float)deg, 1.0f);
    float sinv = deg > 0 ? rsqrtf((float)deg) : 0.f;
    bf16x8 xv = *(const bf16x8*)&xr[(size_t)node * 128 + o8 * 8];
    bf16x8 ov;
    #pragma unroll
    for (int j = 0; j < 8; ++j) {
        float v = fmaxf(acc[j] * rinv + bf2f((ushort)xv[j]) + bl[o8 * 8 + j], 0.f) * sinv;
        ov[j] = (short)f2bf(v);
    }
    *(bf16x8*)&r1s[(size_t)node * 128 + o8 * 8] = ov;
}

// ---------------- gather sum: g = bf16(sum of r1s rows) ----------------
__global__ void gather_sum(const ushort* __restrict__ src,
                           const int* __restrict__ off, const int* __restrict__ slist,
                           ushort* __restrict__ dst) {
    int gt = blockIdx.x * 256 + threadIdx.x;
    int node = gt >> 4;
    if (node >= N_ORIG) return;
    int o8 = gt & 15;
    int s = off[node], e = off[node + 1];
    float acc[8] = {0.f, 0.f, 0.f, 0.f, 0.f, 0.f, 0.f, 0.f};
    for (int i = s; i < e; ++i) {
        int sn = slist[i];
        bf16x8 v = *(const bf16x8*)&src[(size_t)sn * 128 + o8 * 8];
        #pragma unroll
        for (int j = 0; j < 8; ++j) acc[j] += bf2f((ushort)v[j]);
    }
    bf16x8 ov;
    #pragma unroll
    for (int j = 0; j < 8; ++j) ov[j] = (short)f2bf(acc[j]);
    *(bf16x8*)&dst[(size_t)node * 128 + o8 * 8] = ov;
}

// ---- fused double-GEMM (NO gather): t = relu(g@Wg2*inv_d + bg2); out = t@Wout + bout ----
__global__ __launch_bounds__(256) void gemm_t_out(
    const ushort* __restrict__ g, const ushort* __restrict__ WTg,
    const ushort* __restrict__ WTo, const int* __restrict__ off,
    const float* __restrict__ bg, const float* __restrict__ bo,
    float* __restrict__ out, int M) {
    __shared__ ushort Alds[64 * 128];    // 16 KB
    __shared__ ushort Wlds[128 * 128];   // 32 KB
    const int t = threadIdx.x;
    const int i0 = blockIdx.x * 64;

    // stage Wg2^T + A (bf16 direct copy)
    #pragma unroll
    for (int it = 0; it < 8; ++it) {
        int idx = t + 256 * it;
        int n = idx >> 4, u = idx & 15;
        *(bf16x8*)&Wlds[swz(n * 256 + u * 16) >> 1] = *(const bf16x8*)&WTg[idx * 8];
    }
    #pragma unroll
    for (int it = 0; it < 4; ++it) {
        int idx = t + 256 * it;
        int row = idx >> 4, u = idx & 15;
        int gr = min(i0 + row, M - 1);
        bf16x8 v = *(const bf16x8*)&g[(size_t)gr * 128 + u * 8];
        *(bf16x8*)&Alds[swz(row * 256 + u * 16) >> 1] = v;
    }
    __syncthreads();

    const int w = t >> 6, l = t & 63;
    const int r16 = l & 15, kg = l >> 4;
    const int arow = 16 * w + r16;

    bf16x8 a[4];
    #pragma unroll
    for (int ks = 0; ks < 4; ++ks)
        a[ks] = *(const bf16x8*)&Alds[swz(arow * 256 + kg * 16 + ks * 64) >> 1];
    f32x4 acc[8];
    #pragma unroll
    for (int cf = 0; cf < 8; ++cf) acc[cf] = (f32x4){0.f, 0.f, 0.f, 0.f};
    #pragma unroll
    for (int cf = 0; cf < 8; ++cf) {
        int n = cf * 16 + r16;
        #pragma unroll
        for (int ks = 0; ks < 4; ++ks) {
            bf16x8 b = *(const bf16x8*)&Wlds[swz(n * 256 + kg * 16 + ks * 64) >> 1];
            acc[cf] = __builtin_amdgcn_mfma_f32_16x16x32_bf16(a[ks], b, acc[cf], 0, 0, 0);
        }
    }
    __syncthreads();   // Alds a-frags in regs, Wlds consumed -> both reusable

    // t-tile = relu(acc*inv_d + bg) -> Alds (bf16, swizzled); stage Wout^T -> Wlds
    #pragma unroll
    for (int r = 0; r < 4; ++r) {
        int row = 16 * w + 4 * kg + r;
        int grc = min(i0 + row, M - 1);
        int dg = off[grc + 1] - off[grc];
        float di = dg > 0 ? rsqrtf((float)dg) : 0.f;
        #pragma unroll
        for (int cf = 0; cf < 8; ++cf) {
            int col = cf * 16 + r16;
            float v = fmaxf(acc[cf][r] * di + bg[col], 0.f);
            Alds[swz(row * 256 + col * 2) >> 1] = f2bf(v);
        }
    }
    #pragma unroll
    for (int it = 0; it < 4; ++it) {
        int idx = t + 256 * it;
        int n = idx >> 4, u = idx & 15;
        *(bf16x8*)&Wlds[swz(n * 256 + u * 16) >> 1] = *(const bf16x8*)&WTo[idx * 8];
    }
    __syncthreads();

    bf16x8 a2[4];
    #pragma unroll
    for (int ks = 0; ks < 4; ++ks)
        a2[ks] = *(const bf16x8*)&Alds[swz(arow * 256 + kg * 16 + ks * 64) >> 1];
    f32x4 acc2[4];
    #pragma unroll
    for (int cf = 0; cf < 4; ++cf) acc2[cf] = (f32x4){0.f, 0.f, 0.f, 0.f};
    #pragma unroll
    for (int cf = 0; cf < 4; ++cf) {
        int n = cf * 16 + r16;
        #pragma unroll
        for (int ks = 0; ks < 4; ++ks) {
            bf16x8 b = *(const bf16x8*)&Wlds[swz(n * 256 + kg * 16 + ks * 64) >> 1];
            acc2[cf] = __builtin_amdgcn_mfma_f32_16x16x32_bf16(a2[ks], b, acc2[cf], 0, 0, 0);
        }
    }
    #pragma unroll
    for (int r = 0; r < 4; ++r) {
        int gr = i0 + 16 * w + 4 * kg + r;
        if (gr >= M) continue;
        #pragma unroll
        for (int cf = 0; cf < 4; ++cf) {
            int col = cf * 16 + r16;
            out[(size_t)gr * 64 + col] = acc2[cf][r] + bo[col];
        }
    }
}

extern "C" void kernel_launch(void* const* d_in, const int* in_sizes, int n_in,
                              void* d_out, int out_size, void* d_ws, size_t ws_size,
                              hipStream_t stream) {
    const float* x_ret    = (const float*)d_in[0];
    const float* x_orig   = (const float*)d_in[1];
    const int*   ret_idx  = (const int*)d_in[2];
    const int*   orig_idx = (const int*)d_in[3];
    const float* Wl1  = (const float*)d_in[6];
    const float* bl1  = (const float*)d_in[7];
    const float* Wr1  = (const float*)d_in[8];
    const float* Wg2  = (const float*)d_in[9];
    const float* bg2  = (const float*)d_in[10];
    const float* Wout = (const float*)d_in[14];
    const float* bout = (const float*)d_in[15];
    float* out = (float*)d_out;

    // workspace layout
    ushort* hoB  = (ushort*)d_ws;                       // 100k*128 bf16 (ho, later g)
    ushort* xrB  = hoB + (size_t)N_ORIG * 128;          // 200k*128 bf16
    ushort* r1sB = xrB + (size_t)N_RET * 128;           // 200k*128 bf16
    ushort* wtl1 = r1sB + (size_t)N_RET * 128;          // 16384
    ushort* wtr1 = wtl1 + 16384;                        // 16384
    ushort* wtg2 = wtr1 + 16384;                        // 16384
    ushort* wto  = wtg2 + 16384;                        // 8192
    int* off_ret  = (int*)(wto + 8192);                 // N_RET+1
    int* off_orig = off_ret + N_RET + 1;                // N_ORIG+1
    int* bcnt1    = off_orig + N_ORIG + 1;              // 512
    int* bcnt2    = bcnt1 + 512;                        // 512 (adjacent for one-pass zero)
    int* boff1    = bcnt2 + 512;                        // 512
    int* boff2    = boff1 + 512;                        // 512
    int* bcur1    = boff2 + 512;                        // 512
    int* bcur2    = bcur1 + 512;                        // 512
    int* el1      = bcur2 + 512;                        // N_EDGE (src=orig, grouped by ret)
    int* el2      = el1 + N_EDGE;                       // N_EDGE (src=ret, grouped by orig)
    int* binned1  = el2 + N_EDGE;                       // N_EDGE packed
    int* binned2  = binned1 + N_EDGE;                   // N_EDGE packed

    prep_kernel<<<225, 256, 0, stream>>>(Wl1, Wr1, Wg2, Wout, wtl1, wtr1, wtg2, wto, bcnt1);

    bucket_count<<<NBIN, 256, 0, stream>>>(ret_idx, orig_idx, bcnt1, bcnt2);
    scan_buckets<<<1, 256, 0, stream>>>(bcnt1, boff1, bcur1, bcnt2, boff2, bcur2,
                                        off_ret, off_orig);
    bin_both<<<2 * NBIN, 256, 0, stream>>>(ret_idx, orig_idx, bcur1, bcur2, binned1, binned2);
    fill_both<<<NB_RET + NB_ORIG, 256, 0, stream>>>(binned1, boff1, off_ret, el1,
                                                    binned2, boff2, off_orig, el2);

    // ho = bf16(x_orig @ Wl1); xr = bf16(x_ret @ Wr1)   (one dispatch)
    gemm_lin<<<NBLK_HO + NBLK_XR, 256, 0, stream>>>(
        (const float4*)x_orig, (const float4*)x_ret, wtl1, wtr1, hoB, xrB);

    // r1s = bf16(relu(mean_agg(ho) + xr + bl1) * inv_s)   [200k x 128]
    gather_sage<<<(N_RET * 16) / 256, 256, 0, stream>>>(hoB, xrB, off_ret, el1, bl1, r1sB);

    // g = bf16(segment_sum(r1s))          [100k x 128]  (reuses hoB)
    gather_sum<<<(N_ORIG * 16) / 256, 256, 0, stream>>>(r1sB, off_orig, el2, hoB);

    // t = relu(g@Wg2*inv_d + bg2); out = t@Wout + bout   (fused, gather-free)
    gemm_t_out<<<(N_ORIG + 63) / 64, 256, 0, stream>>>(hoB, wtg2, wto, off_orig,
                                                       bg2, bout, out, N_ORIG);
}